// Round 1
// 3229.653 us; speedup vs baseline: 1.1007x; 1.1007x over previous
//
#include <hip/hip_runtime.h>
#include <hip/hip_bf16.h>
#include <math.h>

// Problem constants
#define NTOK 8192   // B*L tokens
#define DDIM 2048
#define EEXP 8
#define HDIM 8192
// GEMM tiling (m97-style)
#define BM 128
#define BN 128
#define BK 64

typedef __attribute__((ext_vector_type(8))) short short8;
typedef __attribute__((ext_vector_type(4))) float f32x4;
typedef __attribute__((ext_vector_type(2))) unsigned int u32x2;

// ws layout (bytes); total required ≈ 303 MB
#define WS_CNT   0                            // int[8]   atomic counters == final counts
#define WS_BASE  64                           // int[9]   prefix sums
#define WS_LIST  1024                         // int[8][8192] token lists
#define WS_GATE  (1024 + EEXP*NTOK*4)         // float[8][8192] gate weights
#define WS_XB    (1u<<20)                     // ushort[8192][2048] x in bf16
#define WS_H     (WS_XB + (size_t)NTOK*DDIM*2) // ushort[16384][8192] h in bf16

__device__ __forceinline__ unsigned short f2bf(float f) {
  union { float f; unsigned int u; } v; v.f = f;
  unsigned int r = v.u + 0x7fffu + ((v.u >> 16) & 1u);
  return (unsigned short)(r >> 16);
}

// Packed fp32x2 -> bf16x2 (RNE, matches f2bf). No builtin on gfx950 (m240);
// inline asm. dst.lo = bf16(lo), dst.hi = bf16(hi).
__device__ __forceinline__ unsigned int cvt_pk_bf16(float lo, float hi) {
  unsigned int r;
  asm("v_cvt_pk_bf16_f32 %0, %1, %2" : "=v"(r) : "v"(lo), "v"(hi));
  return r;
}

#define GLD_LDS16(g, l)                                                        \
  __builtin_amdgcn_global_load_lds((__attribute__((address_space(1))) void*)(g), \
                                   (__attribute__((address_space(3))) void*)(l), \
                                   16, 0, 0)

// ---------------------------------------------------------------------------
// Kernel 1: gating. One block per token: 8 logits, top-2, softmax-of-2,
// append to per-expert lists; also emit bf16 copy of x. float4-vectorized.
// ---------------------------------------------------------------------------
__global__ __launch_bounds__(256) void gate_kernel(
    const float* __restrict__ x, const float* __restrict__ gw,
    unsigned short* __restrict__ xb, int* __restrict__ cnt,
    int* __restrict__ list, float* __restrict__ gatev)
{
  __shared__ float red[EEXP][256];
  const int tid = threadIdx.x;
  const int t = blockIdx.x;
  const float4* xr4 = (const float4*)(x + (size_t)t * DDIM);
  const float4* gw4 = (const float4*)gw;
  float acc[EEXP];
#pragma unroll
  for (int e = 0; e < EEXP; ++e) acc[e] = 0.f;
#pragma unroll
  for (int it = 0; it < DDIM / 4 / 256; ++it) {
    int d4 = tid + it * 256;
    float4 xv = xr4[d4];
    u32x2 pk;
    pk[0] = cvt_pk_bf16(xv.x, xv.y);
    pk[1] = cvt_pk_bf16(xv.z, xv.w);
    *(u32x2*)(xb + (size_t)t * DDIM + d4 * 4) = pk;
#pragma unroll
    for (int e = 0; e < EEXP; ++e) {
      float4 g = gw4[e * (DDIM / 4) + d4];
      acc[e] += xv.x * g.x + xv.y * g.y + xv.z * g.z + xv.w * g.w;
    }
  }
#pragma unroll
  for (int e = 0; e < EEXP; ++e) red[e][tid] = acc[e];
  __syncthreads();
  for (int s = 128; s > 0; s >>= 1) {
    if (tid < s) {
#pragma unroll
      for (int e = 0; e < EEXP; ++e) red[e][tid] += red[e][tid + s];
    }
    __syncthreads();
  }
  if (tid == 0) {
    float l[EEXP];
#pragma unroll
    for (int e = 0; e < EEXP; ++e) l[e] = red[e][0];
    int i0 = 0;
#pragma unroll
    for (int e = 1; e < EEXP; ++e) if (l[e] > l[i0]) i0 = e;
    int i1 = (i0 == 0) ? 1 : 0;
#pragma unroll
    for (int e = 0; e < EEXP; ++e) { if (e != i0 && l[e] > l[i1]) i1 = e; }
    float ex = expf(l[i1] - l[i0]);   // <= 1
    float g0 = 1.f / (1.f + ex);
    float g1 = ex / (1.f + ex);
    int p0 = atomicAdd(&cnt[i0], 1);
    list[i0 * NTOK + p0] = t; gatev[i0 * NTOK + p0] = g0;
    int p1 = atomicAdd(&cnt[i1], 1);
    list[i1 * NTOK + p1] = t; gatev[i1 * NTOK + p1] = g1;
  }
}

// ---------------------------------------------------------------------------
// Kernel 2: prefix sums over counts + load-balance loss.
// ---------------------------------------------------------------------------
__global__ void prefix_loss_kernel(const int* __restrict__ cnt,
                                   int* __restrict__ base,
                                   float* __restrict__ loss_out)
{
  if (threadIdx.x == 0 && blockIdx.x == 0) {
    int b = 0;
    for (int e = 0; e < EEXP; ++e) { base[e] = b; b += cnt[e]; }
    base[EEXP] = b;
    float tot = (float)b;  // = NTOK*K = 16384
    float loss = 0.f;
    for (int e = 0; e < EEXP; ++e) {
      float p = (float)cnt[e] / tot - 0.125f;
      loss += p * p;
    }
    *loss_out = loss * 0.125f;  // mean over E=8
  }
}

// ---------------------------------------------------------------------------
// Kernel 3: grouped GEMM1  h = gelu(x_gathered · w1[e]^T), h stored bf16.
// grid = (HDIM/BN, 512): y slot = e*64 + row-tile. A gathered via token list.
// LDS tiles XOR-swizzled (byte ^= (row&7)<<4) to kill the 16-way ds_read_b128
// bank conflict of the 128B-stride row-major layout (G4 / m201 st-swizzle).
// sA is filled by global_load_lds (linear dest) -> swizzle via pre-swizzled
// per-lane global source column (m173). sB is reg-staged -> swizzled ds_write.
// ---------------------------------------------------------------------------
__global__ __launch_bounds__(256) void gemm1_kernel(
    const unsigned short* __restrict__ xb, const float* __restrict__ w1,
    unsigned short* __restrict__ hbuf,
    const int* __restrict__ cnt, const int* __restrict__ base,
    const int* __restrict__ list)
{
  __shared__ unsigned short sA[BM * BK];
  __shared__ unsigned short sB[BN * BK];
  __shared__ int sTok[BM];

  const int e = blockIdx.y >> 6;
  const int tilem = blockIdx.y & 63;
  const int Me = cnt[e];
  if (tilem * BM >= Me) return;
  const int cb = blockIdx.x * BN;
  const int tid = threadIdx.x;
  const int lane = tid & 63;
  const int wave = tid >> 6;

  if (tid < BM) {
    int pos = tilem * BM + tid;
    sTok[tid] = list[e * NTOK + min(pos, Me - 1)];
  }
  __syncthreads();

  const float* w1e = w1 + (size_t)e * HDIM * DDIM;

  // A staging: LDS slot chunk (tid&7) of row (tid>>3)+32s receives global
  // chunk ((tid&7) ^ (row&7)); row&7 == (tid>>3)&7 (32s ≡ 0 mod 8).
  const int acol = (((tid & 7) ^ ((tid >> 3) & 7)) * 8);
  const unsigned short* aptr[4];
#pragma unroll
  for (int s = 0; s < 4; ++s) {
    int r = (tid >> 3) + 32 * s;
    aptr[s] = xb + (size_t)sTok[r] * DDIM + acol;
  }
  // B staging: chunk = tid + 256*i2 -> n = (tid>>4)+16*i2, k4 = tid&15.
  // (n&7) == (tid>>4)&7 constant across i2. Swizzled 8B ds_write offsets.
  const int k4 = tid & 15;
  const int n0 = tid >> 4;
  const int bswz = (n0 & 7) << 4;
  const float* bptr[8];
  int boffb[8];
#pragma unroll
  for (int i2 = 0; i2 < 8; ++i2) {
    int n = n0 + 16 * i2;
    bptr[i2] = w1e + (size_t)(cb + n) * DDIM + k4 * 4;
    boffb[i2] = n * 128 + ((k4 * 8) ^ bswz);
  }

  f32x4 acc[4][4];
  const f32x4 zero = {0.f, 0.f, 0.f, 0.f};
#pragma unroll
  for (int i = 0; i < 4; ++i)
#pragma unroll
    for (int j = 0; j < 4; ++j) acc[i][j] = zero;

  const int wm = (wave & 1) * 64;
  const int wn = (wave >> 1) * 64;
  const int quad = lane >> 4;
  const int l16 = lane & 15;
  // fragment-read byte addrs, swizzle-applied: row*128 + ((kk*2+quad*16)^((l16&7)<<4))
  const int rswz = (l16 & 7) << 4;
  int aRow[4], bRow[4];
#pragma unroll
  for (int i = 0; i < 4; ++i) aRow[i] = (wm + i * 16 + l16) * 128;
#pragma unroll
  for (int j = 0; j < 4; ++j) bRow[j] = (wn + j * 16 + l16) * 128;
  const int col0 = (quad * 16) ^ rswz;        // kk = 0
  const int col1 = (64 + quad * 16) ^ rswz;   // kk = 32
  const char* sAc = (const char*)sA;
  const char* sBc = (const char*)sB;

  for (int k0 = 0; k0 < DDIM; k0 += BK) {
    f32x4 bv[8];
#pragma unroll
    for (int i2 = 0; i2 < 8; ++i2)
      bv[i2] = *(const f32x4*)(bptr[i2] + k0);
#pragma unroll
    for (int s = 0; s < 4; ++s)
      GLD_LDS16(aptr[s] + k0, sA + wave * 512 + s * 2048);
#pragma unroll
    for (int i2 = 0; i2 < 8; ++i2) {
      u32x2 pk;
      pk[0] = cvt_pk_bf16(bv[i2][0], bv[i2][1]);
      pk[1] = cvt_pk_bf16(bv[i2][2], bv[i2][3]);
      *(u32x2*)((char*)sB + boffb[i2]) = pk;
    }
    __syncthreads();
#pragma unroll
    for (int kki = 0; kki < 2; ++kki) {
      const int colb = kki ? col1 : col0;
      short8 af[4], bf[4];
#pragma unroll
      for (int i = 0; i < 4; ++i)
        af[i] = *(const short8*)(sAc + aRow[i] + colb);
#pragma unroll
      for (int j = 0; j < 4; ++j)
        bf[j] = *(const short8*)(sBc + bRow[j] + colb);
#pragma unroll
      for (int i = 0; i < 4; ++i)
#pragma unroll
        for (int j = 0; j < 4; ++j)
          acc[i][j] = __builtin_amdgcn_mfma_f32_16x16x32_bf16(af[i], bf[j], acc[i][j], 0, 0, 0);
    }
    __syncthreads();
  }

  const int pb = base[e];
#pragma unroll
  for (int i = 0; i < 4; ++i) {
#pragma unroll
    for (int r = 0; r < 4; ++r) {
      int rowl = wm + i * 16 + quad * 4 + r;
      int pos = tilem * BM + rowl;
      if (pos < Me) {
        size_t hrow = (size_t)(pb + pos) * HDIM + cb + wn;
#pragma unroll
        for (int j = 0; j < 4; ++j) {
          float v = acc[i][j][r];
          float g = 0.5f * v * (1.f + erff(v * 0.70710678118654752440f));  // exact gelu
          hbuf[hrow + j * 16 + l16] = f2bf(g);
        }
      }
    }
  }
}

// ---------------------------------------------------------------------------
// Kernel 4: grouped GEMM2  out[token] += gate * (h · w2[e]^T)  via atomics.
// grid = (DDIM/BN, 512). A rows are contiguous pair rows (no gather).
// Same swizzle scheme as GEMM1.
// ---------------------------------------------------------------------------
__global__ __launch_bounds__(256) void gemm2_kernel(
    const unsigned short* __restrict__ hbuf, const float* __restrict__ w2,
    float* __restrict__ out,
    const int* __restrict__ cnt, const int* __restrict__ base,
    const int* __restrict__ list, const float* __restrict__ gatev)
{
  __shared__ unsigned short sA[BM * BK];
  __shared__ unsigned short sB[BN * BK];
  __shared__ int sTok[BM];
  __shared__ float sGate[BM];

  const int e = blockIdx.y >> 6;
  const int tilem = blockIdx.y & 63;
  const int Me = cnt[e];
  if (tilem * BM >= Me) return;
  const int cb = blockIdx.x * BN;
  const int tid = threadIdx.x;
  const int lane = tid & 63;
  const int wave = tid >> 6;
  const int pb = base[e];

  if (tid < BM) {
    int pos = tilem * BM + tid;
    int posc = min(pos, Me - 1);
    sTok[tid] = list[e * NTOK + posc];
    sGate[tid] = gatev[e * NTOK + posc];
  }
  __syncthreads();

  const float* w2e = w2 + (size_t)e * DDIM * HDIM;

  const int acol = (((tid & 7) ^ ((tid >> 3) & 7)) * 8);
  const unsigned short* aptr[4];
#pragma unroll
  for (int s = 0; s < 4; ++s) {
    int pos = tilem * BM + (tid >> 3) + 32 * s;
    aptr[s] = hbuf + (size_t)(pb + min(pos, Me - 1)) * HDIM + acol;
  }
  const int k4 = tid & 15;
  const int n0 = tid >> 4;
  const int bswz = (n0 & 7) << 4;
  const float* bptr[8];
  int boffb[8];
#pragma unroll
  for (int i2 = 0; i2 < 8; ++i2) {
    int n = n0 + 16 * i2;
    bptr[i2] = w2e + (size_t)(cb + n) * HDIM + k4 * 4;
    boffb[i2] = n * 128 + ((k4 * 8) ^ bswz);
  }

  f32x4 acc[4][4];
  const f32x4 zero = {0.f, 0.f, 0.f, 0.f};
#pragma unroll
  for (int i = 0; i < 4; ++i)
#pragma unroll
    for (int j = 0; j < 4; ++j) acc[i][j] = zero;

  const int wm = (wave & 1) * 64;
  const int wn = (wave >> 1) * 64;
  const int quad = lane >> 4;
  const int l16 = lane & 15;
  const int rswz = (l16 & 7) << 4;
  int aRow[4], bRow[4];
#pragma unroll
  for (int i = 0; i < 4; ++i) aRow[i] = (wm + i * 16 + l16) * 128;
#pragma unroll
  for (int j = 0; j < 4; ++j) bRow[j] = (wn + j * 16 + l16) * 128;
  const int col0 = (quad * 16) ^ rswz;
  const int col1 = (64 + quad * 16) ^ rswz;
  const char* sAc = (const char*)sA;
  const char* sBc = (const char*)sB;

  for (int k0 = 0; k0 < HDIM; k0 += BK) {
    f32x4 bv[8];
#pragma unroll
    for (int i2 = 0; i2 < 8; ++i2)
      bv[i2] = *(const f32x4*)(bptr[i2] + k0);
#pragma unroll
    for (int s = 0; s < 4; ++s)
      GLD_LDS16(aptr[s] + k0, sA + wave * 512 + s * 2048);
#pragma unroll
    for (int i2 = 0; i2 < 8; ++i2) {
      u32x2 pk;
      pk[0] = cvt_pk_bf16(bv[i2][0], bv[i2][1]);
      pk[1] = cvt_pk_bf16(bv[i2][2], bv[i2][3]);
      *(u32x2*)((char*)sB + boffb[i2]) = pk;
    }
    __syncthreads();
#pragma unroll
    for (int kki = 0; kki < 2; ++kki) {
      const int colb = kki ? col1 : col0;
      short8 af[4], bf[4];
#pragma unroll
      for (int i = 0; i < 4; ++i)
        af[i] = *(const short8*)(sAc + aRow[i] + colb);
#pragma unroll
      for (int j = 0; j < 4; ++j)
        bf[j] = *(const short8*)(sBc + bRow[j] + colb);
#pragma unroll
      for (int i = 0; i < 4; ++i)
#pragma unroll
        for (int j = 0; j < 4; ++j)
          acc[i][j] = __builtin_amdgcn_mfma_f32_16x16x32_bf16(af[i], bf[j], acc[i][j], 0, 0, 0);
    }
    __syncthreads();
  }

#pragma unroll
  for (int i = 0; i < 4; ++i) {
#pragma unroll
    for (int r = 0; r < 4; ++r) {
      int rowl = wm + i * 16 + quad * 4 + r;
      int pos = tilem * BM + rowl;
      if (pos < Me) {
        int tok = sTok[rowl];
        float gt = sGate[rowl];
        float* orow = out + (size_t)tok * DDIM + cb + wn;
#pragma unroll
        for (int j = 0; j < 4; ++j)
          unsafeAtomicAdd(orow + j * 16 + l16, gt * acc[i][j][r]);
      }
    }
  }
}

// ---------------------------------------------------------------------------
extern "C" void kernel_launch(void* const* d_in, const int* in_sizes, int n_in,
                              void* d_out, int out_size, void* d_ws, size_t ws_size,
                              hipStream_t stream)
{
  const float* x  = (const float*)d_in[0];
  const float* gw = (const float*)d_in[1];
  const float* w1 = (const float*)d_in[2];
  const float* w2 = (const float*)d_in[3];
  float* out = (float*)d_out;
  char* ws = (char*)d_ws;

  int*   cnt   = (int*)(ws + WS_CNT);
  int*   base  = (int*)(ws + WS_BASE);
  int*   list  = (int*)(ws + WS_LIST);
  float* gatev = (float*)(ws + WS_GATE);
  unsigned short* xb = (unsigned short*)(ws + WS_XB);
  unsigned short* hb = (unsigned short*)(ws + WS_H);

  // zero output (GEMM2 accumulates atomically) and counters
  hipMemsetAsync(d_out, 0, (size_t)out_size * sizeof(float), stream);
  hipMemsetAsync(ws, 0, 1024, stream);

  gate_kernel<<<NTOK, 256, 0, stream>>>(x, gw, xb, cnt, list, gatev);
  prefix_loss_kernel<<<1, 64, 0, stream>>>(cnt, base, out + (size_t)NTOK * DDIM);
  gemm1_kernel<<<dim3(HDIM / BN, 512), 256, 0, stream>>>(xb, w1, hb, cnt, base, list);
  gemm2_kernel<<<dim3(DDIM / BN, 512), 256, 0, stream>>>(hb, w2, out, cnt, base, list, gatev);
}